// Round 14
// baseline (111.858 us; speedup 1.0000x reference)
//
#include <hip/hip_runtime.h>
#include <math.h>

#define CC 64
#define CQv 8
#define CRv 4
#define BB 4
#define RR 224
#define TT 224
#define NN (RR*TT)   // 50176
#define LOG2E 1.4426950408889634f

typedef __attribute__((ext_vector_type(8))) short short8;
typedef __attribute__((ext_vector_type(4))) float f32x4;

__device__ __forceinline__ f32x4 mfma_bf16(short8 a, short8 b, f32x4 c){
    return __builtin_amdgcn_mfma_f32_16x16x32_bf16(a, b, c, 0, 0, 0);
}

__device__ __forceinline__ ushort f2bf(float f){
    union { float f; unsigned u; } v; v.f = f;
    unsigned r = v.u + 0x7fffu + ((v.u >> 16) & 1u);
    return (ushort)(r >> 16);
}
__device__ __forceinline__ float bf2f(ushort u){
    return __uint_as_float((unsigned)u << 16);
}
// pack two f32 as truncated bf16 pair: [lo=a, hi=b]
__device__ __forceinline__ unsigned packbf(float a, float b){
    return __builtin_amdgcn_perm(__float_as_uint(b), __float_as_uint(a), 0x07060302u);
}
// balanced XOR swizzle: 512B rows (32 slots of 16B)
__device__ __forceinline__ int vswz(int row, int uslot){
    return (uslot ^ (row & 7) ^ ((row >> 3) & 7)) << 4;
}

// ---------------- K1: q,k,v 1x1 convs via MFMA + per-block mean partials ----------------
// qB[b][pos][8], kB[b][pos][8] (k pre-scaled by log2e), vB[b][pos][64]  (bf16)
__global__ __launch_bounds__(256) void k_qkv(
    const float* __restrict__ x,
    const float* __restrict__ Wq, const float* __restrict__ bq,
    const float* __restrict__ Wk, const float* __restrict__ bk,
    const float* __restrict__ Wv, const float* __restrict__ bv,
    ushort* __restrict__ qB, ushort* __restrict__ kB, ushort* __restrict__ vB,
    float* __restrict__ partial)
{
    const int tid = threadIdx.x;
    const int w = tid >> 6, l = tid & 63, l15 = l & 15, lg = l >> 4;
    const int blk = blockIdx.x;
    const int b = blk / 196, pb = blk - b*196;
    const int n0 = pb*256;
    const float* xb = x + (size_t)b*CC*NN;

    short8 afr[5][2];
#pragma unroll
    for (int ot = 0; ot < 5; ++ot) {
        int oo = ot*16 + l15;
        const float* wr = (oo < 8) ? (Wq + oo*64)
                        : (oo < 16) ? (Wk + (oo-8)*64)
                                    : (Wv + (oo-16)*64);
        float scl = (oo >= 8 && oo < 16) ? LOG2E : 1.0f;
#pragma unroll
        for (int ks = 0; ks < 2; ++ks) {
            const float* p = wr + ks*32 + lg*8;
            float4 w0 = *(const float4*)p, w1 = *(const float4*)(p+4);
            short8 f;
            f[0]=f2bf(w0.x*scl); f[1]=f2bf(w0.y*scl); f[2]=f2bf(w0.z*scl); f[3]=f2bf(w0.w*scl);
            f[4]=f2bf(w1.x*scl); f[5]=f2bf(w1.y*scl); f[6]=f2bf(w1.z*scl); f[7]=f2bf(w1.w*scl);
            afr[ot][ks] = f;
        }
    }
    f32x4 binit[5];
#pragma unroll
    for (int ot = 0; ot < 5; ++ot) {
        const float* bp;
        float scl = 1.0f;
        if (ot == 0) { bp = (lg < 2) ? (bq + lg*4) : (bk + (lg-2)*4); if (lg >= 2) scl = LOG2E; }
        else           bp = bv + (ot-1)*16 + lg*4;
        float4 bb4 = *(const float4*)bp;
        binit[ot] = (f32x4){bb4.x*scl, bb4.y*scl, bb4.z*scl, bb4.w*scl};
    }

    float msum[16];
#pragma unroll
    for (int i = 0; i < 16; ++i) msum[i] = 0.f;

#pragma unroll
    for (int j = 0; j < 4; ++j) {
        int n = n0 + (w*4 + j)*16 + l15;
        short8 bfr[2];
#pragma unroll
        for (int ks = 0; ks < 2; ++ks) {
            const float* xp = xb + (size_t)(ks*32 + lg*8)*NN + n;
            short8 f;
#pragma unroll
            for (int e = 0; e < 8; ++e) {
                float xv = xp[(size_t)e*NN];
                f[e] = f2bf(xv);
                msum[ks*8 + e] += xv;
            }
            bfr[ks] = f;
        }
#pragma unroll
        for (int ot = 0; ot < 5; ++ot) {
            f32x4 acc = binit[ot];
            acc = mfma_bf16(afr[ot][0], bfr[0], acc);
            acc = mfma_bf16(afr[ot][1], bfr[1], acc);
            ushort4 pk;
            pk.x = f2bf(acc[0]); pk.y = f2bf(acc[1]);
            pk.z = f2bf(acc[2]); pk.w = f2bf(acc[3]);
            if (ot == 0) {
                ushort* dst = (lg < 2) ? (qB + ((size_t)b*NN + n)*8 + lg*4)
                                       : (kB + ((size_t)b*NN + n)*8 + (lg-2)*4);
                *(ushort4*)dst = pk;
            } else {
                int oc = (ot-1)*16 + lg*4;
                *(ushort4*)(vB + ((size_t)b*NN + n)*64 + oc) = pk;
            }
        }
    }

#pragma unroll
    for (int i = 0; i < 16; ++i) {
        float s = msum[i];
        s += __shfl_xor(s, 1); s += __shfl_xor(s, 2);
        s += __shfl_xor(s, 4); s += __shfl_xor(s, 8);
        msum[i] = s;
    }
    __shared__ float msums[4][4][16];
    if (l15 == 0) {
#pragma unroll
        for (int i = 0; i < 16; ++i) msums[w][lg][i] = msum[i];
    }
    __syncthreads();
    if (tid < 64) {
        int c = tid;
        int lgi = (c >> 3) & 3, ii = (c >> 5)*8 + (c & 7);
        float t = msums[0][lgi][ii] + msums[1][lgi][ii] + msums[2][lgi][ii] + msums[3][lgi][ii];
        partial[(size_t)blk*64 + c] = t;
    }
}

// ---------------- transpose q/k (z<8) + SE branch (z==8, one block) ----------------
__global__ __launch_bounds__(256) void k_tq(const uint4* __restrict__ qs, const uint4* __restrict__ ks,
                                            uint4* __restrict__ qd, uint4* __restrict__ kd,
                                            const float* __restrict__ partial,
                                            const float* __restrict__ W1, const float* __restrict__ W2,
                                            float* __restrict__ y2)
{
    int z = blockIdx.z;
    if (z == 8) {
        if (blockIdx.x || blockIdx.y) return;
        __shared__ float mean_s[4][64];
        int tid = threadIdx.x;
        int b = tid >> 6, c = tid & 63;
        float s = 0.f;
        for (int i = 0; i < 196; ++i) s += partial[((size_t)(b*196 + i))*64 + c];
        mean_s[b][c] = s * (1.0f/NN);
        __syncthreads();
        float h[CRv];
#pragma unroll
        for (int j = 0; j < CRv; ++j) {
            float t = 0.f;
#pragma unroll
            for (int cc = 0; cc < CC; ++cc) t += W1[j*CC + cc] * mean_s[b][cc];
            h[j] = fmaxf(t, 0.f);
        }
        float s2 = 0.f;
#pragma unroll
        for (int j = 0; j < CRv; ++j) s2 += W2[c*CRv + j] * h[j];
        y2[tid] = 1.f/(1.f + __expf(-s2));
        return;
    }
    __shared__ uint4 tile[32][33];
    int b = z & 3;
    const uint4* sp = ((z >= 4) ? ks : qs) + (size_t)b*NN;
    uint4*       dp = ((z >= 4) ? kd : qd) + (size_t)b*NN;
    int t0 = blockIdx.x*32, r0 = blockIdx.y*32;
    int tx = threadIdx.x & 31, ty = threadIdx.x >> 5;
#pragma unroll
    for (int j = 0; j < 4; ++j) { int lr = ty + 8*j; tile[lr][tx] = sp[(size_t)(r0+lr)*224 + t0 + tx]; }
    __syncthreads();
#pragma unroll
    for (int j = 0; j < 4; ++j) { int lt = ty + 8*j; dp[(size_t)(t0+lt)*224 + r0 + tx] = tile[tx][lt]; }
}

// ---------------- PV via MFMA: ALL FOUR chunks per ks sweep (kf/vf read once) ----------------
// kf/vf depend only on ks -> merging chunks {w,w+4,w+8,w+12} into one ks sweep halves
// per-wave b128 reads (84->42) and 4x the independent work per iteration (hides exp2/MFMA
// latency). ks loop stays unroll 1; kf rotation prefetch after the last score MFMA.
// SPILL SENTINEL: FETCH_SIZE must stay ~31MB (rounds 8-10: spill -> 300-456MB).
__global__ __launch_bounds__(256, 3) void k_pv(const ushort* __restrict__ qA, const ushort* __restrict__ kA,
                                               const ushort* __restrict__ qB, const ushort* __restrict__ kB,
                                               const ushort* __restrict__ vB,
                                               ushort* __restrict__ outA, ushort* __restrict__ outB,
                                               float* __restrict__ ZHt, float* __restrict__ ZWt)
{
    __shared__ __align__(16) ushort Vt[64*256];  // bf16 [c][u'], XOR-swizzled 512B rows (32 KB)
    __shared__ __align__(16) ushort Kh[224*8];   // bf16 K rows (3.5 KB)

    const int tid = threadIdx.x;
    const int bid = blockIdx.x;
    const bool HM = bid < BB*224;
    const int blk = HM ? bid : bid - BB*224;
    const int b = blk / 224, o = blk - b*224;
    const ushort* Qsrc = (HM ? qA : qB) + (size_t)blk*1792;
    const ushort* Ksrc = (HM ? kA : kB) + (size_t)blk*1792;
    ushort* op = (HM ? outA : outB) + (size_t)blk*14336;
    float*  Zt = (HM ? ZHt : ZWt) + (size_t)blk*224;

    // ---- stage V^T with permuted u: u = ks*32 + th*16 + quad*4 + g  ->  u' = ks*32 + quad*8 + th*4 + g
    {
        const uint4* vbase = (const uint4*)vB;
        for (int gi = tid; gi < 448; gi += 256) {
            int ublk = gi >> 3, sub = gi & 7;
            int u0 = ublk << 2;
            size_t base, stride;
            if (HM) { base = ((size_t)b*NN + (size_t)u0*224 + o)*8 + sub; stride = 1792; }
            else    { base = ((size_t)blk*224 + u0)*8 + sub;              stride = 8;    }
            uint4 r0 = vbase[base], r1 = vbase[base+stride], r2 = vbase[base+2*stride], r3 = vbase[base+3*stride];
            const ushort* p0 = (const ushort*)&r0;
            const ushort* p1 = (const ushort*)&r1;
            const ushort* p2 = (const ushort*)&r2;
            const ushort* p3 = (const ushort*)&r3;
            int ks   = ublk >> 3;
            int th   = (ublk >> 2) & 1;
            int quad = ublk & 3;
            int half = th * 8;
#pragma unroll
            for (int j = 0; j < 8; ++j) {
                int c = sub*8 + j;
                ushort4 col; col.x = p0[j]; col.y = p1[j]; col.z = p2[j]; col.w = p3[j];
                *(ushort4*)((char*)Vt + c*512 + vswz(c, ks*4 + quad) + half) = col;
            }
        }
    }
    if (tid < 224) ((uint4*)Kh)[tid] = ((const uint4*)Ksrc)[tid];
    __syncthreads();

    const int w = tid >> 6, l = tid & 63;
    const int l15 = l & 15, lg = l >> 4;
    const short8 zfr = {0,0,0,0,0,0,0,0};
    const f32x4 zacc = {0.f,0.f,0.f,0.f};

    const int ch0 = w, ch1 = w + 4, ch2 = w + 8, ch3 = w + 12;
    const bool do3 = (ch3 < 14);

    short8 qf0 = zfr, qf1 = zfr, qf2 = zfr, qf3 = zfr;
    if (lg == 0) {
        qf0 = *(const short8*)(Qsrc + (size_t)(ch0*16 + l15)*8);
        qf1 = *(const short8*)(Qsrc + (size_t)(ch1*16 + l15)*8);
        qf2 = *(const short8*)(Qsrc + (size_t)(ch2*16 + l15)*8);
        if (do3) qf3 = *(const short8*)(Qsrc + (size_t)(ch3*16 + l15)*8);
    }

    f32x4 acc0[4] = {zacc, zacc, zacc, zacc};
    f32x4 acc1[4] = {zacc, zacc, zacc, zacc};
    f32x4 acc2[4] = {zacc, zacc, zacc, zacc};
    f32x4 acc3[4] = {zacc, zacc, zacc, zacc};
    float zs0 = 0.f, zs1 = 0.f, zs2 = 0.f, zs3 = 0.f;

    short8 kf0c = *(const short8*)(Kh + (size_t)(l15)*8);
    short8 kf1c = *(const short8*)(Kh + (size_t)(16 + l15)*8);

#pragma unroll 1
    for (int ks = 0; ks < 7; ++ks) {
        short8 vf0 = *(const short8*)((const char*)Vt + (size_t)(l15)*512       + vswz(l15,      ks*4 + lg));
        short8 vf1 = *(const short8*)((const char*)Vt + (size_t)(16 + l15)*512  + vswz(16 + l15, ks*4 + lg));
        short8 vf2 = *(const short8*)((const char*)Vt + (size_t)(32 + l15)*512  + vswz(32 + l15, ks*4 + lg));
        short8 vf3 = *(const short8*)((const char*)Vt + (size_t)(48 + l15)*512  + vswz(48 + l15, ks*4 + lg));
        // all score MFMAs up front (chunk3 unconditional: qf3=0 when !do3, outputs unused)
        f32x4 e00 = mfma_bf16(kf0c, qf0, zacc), e01 = mfma_bf16(kf1c, qf0, zacc);
        f32x4 e10 = mfma_bf16(kf0c, qf1, zacc), e11 = mfma_bf16(kf1c, qf1, zacc);
        f32x4 e20 = mfma_bf16(kf0c, qf2, zacc), e21 = mfma_bf16(kf1c, qf2, zacc);
        f32x4 e30 = mfma_bf16(kf0c, qf3, zacc), e31 = mfma_bf16(kf1c, qf3, zacc);
        // rotate kf (prefetch next iteration's K fragments; hidden under the exps/PV)
        int ksn = (ks == 6) ? 0 : ks + 1;
        short8 kf0n = *(const short8*)(Kh + (size_t)(ksn*32 + l15)*8);
        short8 kf1n = *(const short8*)(Kh + (size_t)(ksn*32 + 16 + l15)*8);

        // ---- chunk 0
        {
            float a0[4], a1[4];
#pragma unroll
            for (int g = 0; g < 4; ++g) { a0[g] = __builtin_amdgcn_exp2f(e00[g]); a1[g] = __builtin_amdgcn_exp2f(e01[g]); }
            if (HM && (ch0 >> 1) == ks) {
                if ((ch0 & 1) == 0) {
#pragma unroll
                    for (int g = 0; g < 4; ++g) { if (lg*4 + g == l15) a0[g] = 0.f; }
                } else {
#pragma unroll
                    for (int g = 0; g < 4; ++g) { if (lg*4 + g == l15) a1[g] = 0.f; }
                }
            }
            zs0 += ((a0[0]+a0[1]) + (a0[2]+a0[3])) + ((a1[0]+a1[1]) + (a1[2]+a1[3]));
            int4 ii;
            ii.x = (int)packbf(a0[0], a0[1]); ii.y = (int)packbf(a0[2], a0[3]);
            ii.z = (int)packbf(a1[0], a1[1]); ii.w = (int)packbf(a1[2], a1[3]);
            short8 af = *(short8*)&ii;
            acc0[0] = mfma_bf16(vf0, af, acc0[0]);
            acc0[1] = mfma_bf16(vf1, af, acc0[1]);
            acc0[2] = mfma_bf16(vf2, af, acc0[2]);
            acc0[3] = mfma_bf16(vf3, af, acc0[3]);
        }
        // ---- chunk 1
        {
            float a0[4], a1[4];
#pragma unroll
            for (int g = 0; g < 4; ++g) { a0[g] = __builtin_amdgcn_exp2f(e10[g]); a1[g] = __builtin_amdgcn_exp2f(e11[g]); }
            if (HM && (ch1 >> 1) == ks) {
                if ((ch1 & 1) == 0) {
#pragma unroll
                    for (int g = 0; g < 4; ++g) { if (lg*4 + g == l15) a0[g] = 0.f; }
                } else {
#pragma unroll
                    for (int g = 0; g < 4; ++g) { if (lg*4 + g == l15) a1[g] = 0.f; }
                }
            }
            zs1 += ((a0[0]+a0[1]) + (a0[2]+a0[3])) + ((a1[0]+a1[1]) + (a1[2]+a1[3]));
            int4 ii;
            ii.x = (int)packbf(a0[0], a0[1]); ii.y = (int)packbf(a0[2], a0[3]);
            ii.z = (int)packbf(a1[0], a1[1]); ii.w = (int)packbf(a1[2], a1[3]);
            short8 af = *(short8*)&ii;
            acc1[0] = mfma_bf16(vf0, af, acc1[0]);
            acc1[1] = mfma_bf16(vf1, af, acc1[1]);
            acc1[2] = mfma_bf16(vf2, af, acc1[2]);
            acc1[3] = mfma_bf16(vf3, af, acc1[3]);
        }
        // ---- chunk 2
        {
            float a0[4], a1[4];
#pragma unroll
            for (int g = 0; g < 4; ++g) { a0[g] = __builtin_amdgcn_exp2f(e20[g]); a1[g] = __builtin_amdgcn_exp2f(e21[g]); }
            if (HM && (ch2 >> 1) == ks) {
                if ((ch2 & 1) == 0) {
#pragma unroll
                    for (int g = 0; g < 4; ++g) { if (lg*4 + g == l15) a0[g] = 0.f; }
                } else {
#pragma unroll
                    for (int g = 0; g < 4; ++g) { if (lg*4 + g == l15) a1[g] = 0.f; }
                }
            }
            zs2 += ((a0[0]+a0[1]) + (a0[2]+a0[3])) + ((a1[0]+a1[1]) + (a1[2]+a1[3]));
            int4 ii;
            ii.x = (int)packbf(a0[0], a0[1]); ii.y = (int)packbf(a0[2], a0[3]);
            ii.z = (int)packbf(a1[0], a1[1]); ii.w = (int)packbf(a1[2], a1[3]);
            short8 af = *(short8*)&ii;
            acc2[0] = mfma_bf16(vf0, af, acc2[0]);
            acc2[1] = mfma_bf16(vf1, af, acc2[1]);
            acc2[2] = mfma_bf16(vf2, af, acc2[2]);
            acc2[3] = mfma_bf16(vf3, af, acc2[3]);
        }
        // ---- chunk 3 (guarded; wave-uniform branch)
        if (do3) {
            float a0[4], a1[4];
#pragma unroll
            for (int g = 0; g < 4; ++g) { a0[g] = __builtin_amdgcn_exp2f(e30[g]); a1[g] = __builtin_amdgcn_exp2f(e31[g]); }
            if (HM && (ch3 >> 1) == ks) {
                if ((ch3 & 1) == 0) {
#pragma unroll
                    for (int g = 0; g < 4; ++g) { if (lg*4 + g == l15) a0[g] = 0.f; }
                } else {
#pragma unroll
                    for (int g = 0; g < 4; ++g) { if (lg*4 + g == l15) a1[g] = 0.f; }
                }
            }
            zs3 += ((a0[0]+a0[1]) + (a0[2]+a0[3])) + ((a1[0]+a1[1]) + (a1[2]+a1[3]));
            int4 ii;
            ii.x = (int)packbf(a0[0], a0[1]); ii.y = (int)packbf(a0[2], a0[3]);
            ii.z = (int)packbf(a1[0], a1[1]); ii.w = (int)packbf(a1[2], a1[3]);
            short8 af = *(short8*)&ii;
            acc3[0] = mfma_bf16(vf0, af, acc3[0]);
            acc3[1] = mfma_bf16(vf1, af, acc3[1]);
            acc3[2] = mfma_bf16(vf2, af, acc3[2]);
            acc3[3] = mfma_bf16(vf3, af, acc3[3]);
        }
        kf0c = kf0n; kf1c = kf1n;
    }

    // z row-sums + stores per chunk
    zs0 += __shfl_xor(zs0, 16); zs0 += __shfl_xor(zs0, 32);
    zs1 += __shfl_xor(zs1, 16); zs1 += __shfl_xor(zs1, 32);
    zs2 += __shfl_xor(zs2, 16); zs2 += __shfl_xor(zs2, 32);
    zs3 += __shfl_xor(zs3, 16); zs3 += __shfl_xor(zs3, 32);
    if (lg == 0) {
        Zt[ch0*16 + l15] = zs0;
        Zt[ch1*16 + l15] = zs1;
        Zt[ch2*16 + l15] = zs2;
        if (do3) Zt[ch3*16 + l15] = zs3;
    }
    {
        int pos = ch0*16 + l15;
#pragma unroll
        for (int ct = 0; ct < 4; ++ct) {
            ushort4 pk;
            pk.x = f2bf(acc0[ct][0]); pk.y = f2bf(acc0[ct][1]);
            pk.z = f2bf(acc0[ct][2]); pk.w = f2bf(acc0[ct][3]);
            *(ushort4*)(op + (size_t)pos*64 + ct*16 + lg*4) = pk;
        }
    }
    {
        int pos = ch1*16 + l15;
#pragma unroll
        for (int ct = 0; ct < 4; ++ct) {
            ushort4 pk;
            pk.x = f2bf(acc1[ct][0]); pk.y = f2bf(acc1[ct][1]);
            pk.z = f2bf(acc1[ct][2]); pk.w = f2bf(acc1[ct][3]);
            *(ushort4*)(op + (size_t)pos*64 + ct*16 + lg*4) = pk;
        }
    }
    {
        int pos = ch2*16 + l15;
#pragma unroll
        for (int ct = 0; ct < 4; ++ct) {
            ushort4 pk;
            pk.x = f2bf(acc2[ct][0]); pk.y = f2bf(acc2[ct][1]);
            pk.z = f2bf(acc2[ct][2]); pk.w = f2bf(acc2[ct][3]);
            *(ushort4*)(op + (size_t)pos*64 + ct*16 + lg*4) = pk;
        }
    }
    if (do3) {
        int pos = ch3*16 + l15;
#pragma unroll
        for (int ct = 0; ct < 4; ++ct) {
            ushort4 pk;
            pk.x = f2bf(acc3[ct][0]); pk.y = f2bf(acc3[ct][1]);
            pk.z = f2bf(acc3[ct][2]); pk.w = f2bf(acc3[ct][3]);
            *(ushort4*)(op + (size_t)pos*64 + ct*16 + lg*4) = pk;
        }
    }
}

// ---------------- final: out[b][c][v][t] = x*(1+y2) + (outA + outB) * g/(ZH+ZW) ----------------
__global__ __launch_bounds__(256) void k_final(const float* __restrict__ x,
                                               const ushort* __restrict__ outA,
                                               const ushort* __restrict__ outB,
                                               const float* __restrict__ ZHt,
                                               const float* __restrict__ ZWt,
                                               const float* __restrict__ gammap,
                                               const float* __restrict__ y2,
                                               float* __restrict__ out)
{
    __shared__ float Ls[2][16][65];
    __shared__ float sc[64];
    const int b = blockIdx.z;
    const int v0 = blockIdx.y*16, t0 = blockIdx.x*16;
    const int tid = threadIdx.x;
    const float g = gammap[0];
    if (tid < 64) sc[tid] = 1.f + y2[b*64 + tid];

    const int tl = tid >> 4, cg = tid & 15;   // stage: 16 t-rows x 16 c-quads
    const int tg = tid & 3, cw = tid >> 2;    // write: 64 c-rows x 4 float4

    const ushort* pA = outA + (size_t)b*NN*64;
    const ushort* pB = outB + (size_t)b*NN*64;
    __syncthreads();

    for (int vl = 0; vl < 16; ++vl) {
        const int v = v0 + vl;
        const int buf = vl & 1;
        {   // stage: comb[tl][c] = (A + B)*zi
            const ushort* a4 = pA + ((size_t)(t0 + tl)*224 + v)*64 + cg*4;
            const ushort* b4 = pB + ((size_t)v*224 + (t0 + tl))*64 + cg*4;
            uint2 ra = *(const uint2*)a4;
            uint2 rb = *(const uint2*)b4;
            const ushort* qa = (const ushort*)&ra;
            const ushort* qb = (const ushort*)&rb;
            float zh = ZHt[((size_t)(b*224 + t0 + tl))*224 + v];
            float zw = ZWt[((size_t)(b*224 + v))*224 + t0 + tl];
            float zi = g * __builtin_amdgcn_rcpf(zh + zw);
#pragma unroll
            for (int j = 0; j < 4; ++j)
                Ls[buf][tl][cg*4 + j] = (bf2f(qa[j]) + bf2f(qb[j])) * zi;
        }
        __syncthreads();
        {   // write: out rows [c][v][t0..t0+15], fused with x*(1+y2)
            float s = sc[cw];
            size_t idx = (size_t)(b*64 + cw)*NN + (size_t)v*224 + t0 + tg*4;
            float4 xv = *(const float4*)(x + idx);
            float4 o;
            o.x = xv.x*s + Ls[buf][tg*4+0][cw];
            o.y = xv.y*s + Ls[buf][tg*4+1][cw];
            o.z = xv.z*s + Ls[buf][tg*4+2][cw];
            o.w = xv.w*s + Ls[buf][tg*4+3][cw];
            *(float4*)(out + idx) = o;
        }
    }
}

// ---------------- launcher ----------------
extern "C" void kernel_launch(void* const* d_in, const int* in_sizes, int n_in,
                              void* d_out, int out_size, void* d_ws, size_t ws_size,
                              hipStream_t stream)
{
    const float* x  = (const float*)d_in[0];
    const float* Wq = (const float*)d_in[1];
    const float* bq = (const float*)d_in[2];
    const float* Wk = (const float*)d_in[3];
    const float* bk = (const float*)d_in[4];
    const float* Wv = (const float*)d_in[5];
    const float* bv = (const float*)d_in[6];
    const float* gm = (const float*)d_in[7];
    const float* W1 = (const float*)d_in[8];
    const float* W2 = (const float*)d_in[9];
    float* out = (float*)d_out;

    constexpr size_t QSZ = (size_t)BB*NN*CQv;
    constexpr size_t VSZ = (size_t)BB*NN*CC;
    constexpr size_t SSZ = (size_t)BB*NN;

    ushort* qB = (ushort*)d_ws;
    ushort* kB = qB + QSZ;
    ushort* vB = kB + QSZ;
    ushort* qA = vB + VSZ;
    ushort* kA = qA + QSZ;
    ushort* outA = kA + QSZ;
    ushort* outB = outA + VSZ;
    float*  ZHt = (float*)(outB + VSZ);
    float*  ZWt = ZHt + SSZ;
    float*  partial = ZWt + SSZ;       // BB*196*64 = 50176 floats
    float*  y2 = partial + (size_t)BB*196*64;
    (void)ws_size; (void)in_sizes; (void)n_in; (void)out_size;

    k_qkv<<<BB*196, 256, 0, stream>>>(x, Wq, bq, Wk, bk, Wv, bv, qB, kB, vB, partial);
    k_tq<<<dim3(7,7,9), 256, 0, stream>>>((const uint4*)qB, (const uint4*)kB, (uint4*)qA, (uint4*)kA,
                                          partial, W1, W2, y2);

    k_pv<<<2*BB*224, 256, 0, stream>>>(qA, kA, qB, kB, vB, outA, outB, ZHt, ZWt);

    k_final<<<dim3(14,14,BB), 256, 0, stream>>>(x, outA, outB, ZHt, ZWt, gm, y2, out);
}

// Round 15
// 110.183 us; speedup vs baseline: 1.0152x; 1.0152x over previous
//
#include <hip/hip_runtime.h>
#include <math.h>

#define CC 64
#define CQv 8
#define CRv 4
#define BB 4
#define RR 224
#define TT 224
#define NN (RR*TT)   // 50176
#define LOG2E 1.4426950408889634f

typedef __attribute__((ext_vector_type(8))) short short8;
typedef __attribute__((ext_vector_type(4))) float f32x4;

__device__ __forceinline__ f32x4 mfma_bf16(short8 a, short8 b, f32x4 c){
    return __builtin_amdgcn_mfma_f32_16x16x32_bf16(a, b, c, 0, 0, 0);
}

__device__ __forceinline__ ushort f2bf(float f){
    union { float f; unsigned u; } v; v.f = f;
    unsigned r = v.u + 0x7fffu + ((v.u >> 16) & 1u);
    return (ushort)(r >> 16);
}
__device__ __forceinline__ float bf2f(ushort u){
    return __uint_as_float((unsigned)u << 16);
}
// pack two f32 as truncated bf16 pair: [lo=a, hi=b]
__device__ __forceinline__ unsigned packbf(float a, float b){
    return __builtin_amdgcn_perm(__float_as_uint(b), __float_as_uint(a), 0x07060302u);
}
// balanced XOR swizzle: 512B rows (32 slots of 16B)
__device__ __forceinline__ int vswz(int row, int uslot){
    return (uslot ^ (row & 7) ^ ((row >> 3) & 7)) << 4;
}

// ---------------- K1: q,k,v 1x1 convs via MFMA + per-block mean partials ----------------
// qB[b][pos][8], kB[b][pos][8] (k pre-scaled by log2e), vB[b][pos][64]  (bf16)
__global__ __launch_bounds__(256) void k_qkv(
    const float* __restrict__ x,
    const float* __restrict__ Wq, const float* __restrict__ bq,
    const float* __restrict__ Wk, const float* __restrict__ bk,
    const float* __restrict__ Wv, const float* __restrict__ bv,
    ushort* __restrict__ qB, ushort* __restrict__ kB, ushort* __restrict__ vB,
    float* __restrict__ partial)
{
    const int tid = threadIdx.x;
    const int w = tid >> 6, l = tid & 63, l15 = l & 15, lg = l >> 4;
    const int blk = blockIdx.x;
    const int b = blk / 196, pb = blk - b*196;
    const int n0 = pb*256;
    const float* xb = x + (size_t)b*CC*NN;

    short8 afr[5][2];
#pragma unroll
    for (int ot = 0; ot < 5; ++ot) {
        int oo = ot*16 + l15;
        const float* wr = (oo < 8) ? (Wq + oo*64)
                        : (oo < 16) ? (Wk + (oo-8)*64)
                                    : (Wv + (oo-16)*64);
        float scl = (oo >= 8 && oo < 16) ? LOG2E : 1.0f;
#pragma unroll
        for (int ks = 0; ks < 2; ++ks) {
            const float* p = wr + ks*32 + lg*8;
            float4 w0 = *(const float4*)p, w1 = *(const float4*)(p+4);
            short8 f;
            f[0]=f2bf(w0.x*scl); f[1]=f2bf(w0.y*scl); f[2]=f2bf(w0.z*scl); f[3]=f2bf(w0.w*scl);
            f[4]=f2bf(w1.x*scl); f[5]=f2bf(w1.y*scl); f[6]=f2bf(w1.z*scl); f[7]=f2bf(w1.w*scl);
            afr[ot][ks] = f;
        }
    }
    f32x4 binit[5];
#pragma unroll
    for (int ot = 0; ot < 5; ++ot) {
        const float* bp;
        float scl = 1.0f;
        if (ot == 0) { bp = (lg < 2) ? (bq + lg*4) : (bk + (lg-2)*4); if (lg >= 2) scl = LOG2E; }
        else           bp = bv + (ot-1)*16 + lg*4;
        float4 bb4 = *(const float4*)bp;
        binit[ot] = (f32x4){bb4.x*scl, bb4.y*scl, bb4.z*scl, bb4.w*scl};
    }

    float msum[16];
#pragma unroll
    for (int i = 0; i < 16; ++i) msum[i] = 0.f;

#pragma unroll
    for (int j = 0; j < 4; ++j) {
        int n = n0 + (w*4 + j)*16 + l15;
        short8 bfr[2];
#pragma unroll
        for (int ks = 0; ks < 2; ++ks) {
            const float* xp = xb + (size_t)(ks*32 + lg*8)*NN + n;
            short8 f;
#pragma unroll
            for (int e = 0; e < 8; ++e) {
                float xv = xp[(size_t)e*NN];
                f[e] = f2bf(xv);
                msum[ks*8 + e] += xv;
            }
            bfr[ks] = f;
        }
#pragma unroll
        for (int ot = 0; ot < 5; ++ot) {
            f32x4 acc = binit[ot];
            acc = mfma_bf16(afr[ot][0], bfr[0], acc);
            acc = mfma_bf16(afr[ot][1], bfr[1], acc);
            ushort4 pk;
            pk.x = f2bf(acc[0]); pk.y = f2bf(acc[1]);
            pk.z = f2bf(acc[2]); pk.w = f2bf(acc[3]);
            if (ot == 0) {
                ushort* dst = (lg < 2) ? (qB + ((size_t)b*NN + n)*8 + lg*4)
                                       : (kB + ((size_t)b*NN + n)*8 + (lg-2)*4);
                *(ushort4*)dst = pk;
            } else {
                int oc = (ot-1)*16 + lg*4;
                *(ushort4*)(vB + ((size_t)b*NN + n)*64 + oc) = pk;
            }
        }
    }

#pragma unroll
    for (int i = 0; i < 16; ++i) {
        float s = msum[i];
        s += __shfl_xor(s, 1); s += __shfl_xor(s, 2);
        s += __shfl_xor(s, 4); s += __shfl_xor(s, 8);
        msum[i] = s;
    }
    __shared__ float msums[4][4][16];
    if (l15 == 0) {
#pragma unroll
        for (int i = 0; i < 16; ++i) msums[w][lg][i] = msum[i];
    }
    __syncthreads();
    if (tid < 64) {
        int c = tid;
        int lgi = (c >> 3) & 3, ii = (c >> 5)*8 + (c & 7);
        float t = msums[0][lgi][ii] + msums[1][lgi][ii] + msums[2][lgi][ii] + msums[3][lgi][ii];
        partial[(size_t)blk*64 + c] = t;
    }
}

// ---------------- transpose q/k (z<8) + SE branch (z==8, one block) ----------------
__global__ __launch_bounds__(256) void k_tq(const uint4* __restrict__ qs, const uint4* __restrict__ ks,
                                            uint4* __restrict__ qd, uint4* __restrict__ kd,
                                            const float* __restrict__ partial,
                                            const float* __restrict__ W1, const float* __restrict__ W2,
                                            float* __restrict__ y2)
{
    int z = blockIdx.z;
    if (z == 8) {
        if (blockIdx.x || blockIdx.y) return;
        __shared__ float mean_s[4][64];
        int tid = threadIdx.x;
        int b = tid >> 6, c = tid & 63;
        float s = 0.f;
        for (int i = 0; i < 196; ++i) s += partial[((size_t)(b*196 + i))*64 + c];
        mean_s[b][c] = s * (1.0f/NN);
        __syncthreads();
        float h[CRv];
#pragma unroll
        for (int j = 0; j < CRv; ++j) {
            float t = 0.f;
#pragma unroll
            for (int cc = 0; cc < CC; ++cc) t += W1[j*CC + cc] * mean_s[b][cc];
            h[j] = fmaxf(t, 0.f);
        }
        float s2 = 0.f;
#pragma unroll
        for (int j = 0; j < CRv; ++j) s2 += W2[c*CRv + j] * h[j];
        y2[tid] = 1.f/(1.f + __expf(-s2));
        return;
    }
    __shared__ uint4 tile[32][33];
    int b = z & 3;
    const uint4* sp = ((z >= 4) ? ks : qs) + (size_t)b*NN;
    uint4*       dp = ((z >= 4) ? kd : qd) + (size_t)b*NN;
    int t0 = blockIdx.x*32, r0 = blockIdx.y*32;
    int tx = threadIdx.x & 31, ty = threadIdx.x >> 5;
#pragma unroll
    for (int j = 0; j < 4; ++j) { int lr = ty + 8*j; tile[lr][tx] = sp[(size_t)(r0+lr)*224 + t0 + tx]; }
    __syncthreads();
#pragma unroll
    for (int j = 0; j < 4; ++j) { int lt = ty + 8*j; dp[(size_t)(t0+lt)*224 + r0 + tx] = tile[tx][lt]; }
}

// ---------------- PV via MFMA: chunk pairs, permuted-V, kf rotation prefetch, setprio ----------------
// ROUND-14 POST-MORTEM: 4-chunk merge raised VGPR 52->84, occupancy 27->20%, net -3us.
// This is the round-13 sweet spot (2-chunk pairs, 52 VGPR, 8 waves/SIMD) + s_setprio(1)
// around the compute loop (waves are at DIFFERENT phases - staging vs compute - so
// priority arbitration has role diversity; the regime where setprio paid on attn, m191).
// ks loop stays unroll 1 (rounds 8-10: full unroll / tight caps -> scratch spill).
// SPILL SENTINEL: FETCH_SIZE must stay ~31MB.
__global__ __launch_bounds__(256, 3) void k_pv(const ushort* __restrict__ qA, const ushort* __restrict__ kA,
                                               const ushort* __restrict__ qB, const ushort* __restrict__ kB,
                                               const ushort* __restrict__ vB,
                                               ushort* __restrict__ outA, ushort* __restrict__ outB,
                                               float* __restrict__ ZHt, float* __restrict__ ZWt)
{
    __shared__ __align__(16) ushort Vt[64*256];  // bf16 [c][u'], XOR-swizzled 512B rows (32 KB)
    __shared__ __align__(16) ushort Kh[224*8];   // bf16 K rows (3.5 KB)

    const int tid = threadIdx.x;
    const int bid = blockIdx.x;
    const bool HM = bid < BB*224;
    const int blk = HM ? bid : bid - BB*224;
    const int b = blk / 224, o = blk - b*224;
    const ushort* Qsrc = (HM ? qA : qB) + (size_t)blk*1792;
    const ushort* Ksrc = (HM ? kA : kB) + (size_t)blk*1792;
    ushort* op = (HM ? outA : outB) + (size_t)blk*14336;
    float*  Zt = (HM ? ZHt : ZWt) + (size_t)blk*224;

    // ---- stage V^T with permuted u: u = ks*32 + th*16 + quad*4 + g  ->  u' = ks*32 + quad*8 + th*4 + g
    {
        const uint4* vbase = (const uint4*)vB;
        for (int gi = tid; gi < 448; gi += 256) {
            int ublk = gi >> 3, sub = gi & 7;
            int u0 = ublk << 2;
            size_t base, stride;
            if (HM) { base = ((size_t)b*NN + (size_t)u0*224 + o)*8 + sub; stride = 1792; }
            else    { base = ((size_t)blk*224 + u0)*8 + sub;              stride = 8;    }
            uint4 r0 = vbase[base], r1 = vbase[base+stride], r2 = vbase[base+2*stride], r3 = vbase[base+3*stride];
            const ushort* p0 = (const ushort*)&r0;
            const ushort* p1 = (const ushort*)&r1;
            const ushort* p2 = (const ushort*)&r2;
            const ushort* p3 = (const ushort*)&r3;
            int ks   = ublk >> 3;
            int th   = (ublk >> 2) & 1;
            int quad = ublk & 3;
            int half = th * 8;
#pragma unroll
            for (int j = 0; j < 8; ++j) {
                int c = sub*8 + j;
                ushort4 col; col.x = p0[j]; col.y = p1[j]; col.z = p2[j]; col.w = p3[j];
                *(ushort4*)((char*)Vt + c*512 + vswz(c, ks*4 + quad) + half) = col;
            }
        }
    }
    if (tid < 224) ((uint4*)Kh)[tid] = ((const uint4*)Ksrc)[tid];
    __syncthreads();

    const int w = tid >> 6, l = tid & 63;
    const int l15 = l & 15, lg = l >> 4;
    const short8 zfr = {0,0,0,0,0,0,0,0};
    const f32x4 zacc = {0.f,0.f,0.f,0.f};

    __builtin_amdgcn_s_setprio(1);
#pragma unroll 1
    for (int p = 0; p < 2; ++p) {
        const int ch0 = w + p*8;
        const int ch1 = ch0 + 4;
        const bool do1 = (ch1 < 14);
        short8 qf0 = zfr, qf1 = zfr;
        if (lg == 0) {
            qf0 = *(const short8*)(Qsrc + (size_t)(ch0*16 + l15)*8);
            if (do1) qf1 = *(const short8*)(Qsrc + (size_t)(ch1*16 + l15)*8);
        }
        f32x4 acc00 = zacc, acc01 = zacc, acc02 = zacc, acc03 = zacc;
        f32x4 acc10 = zacc, acc11 = zacc, acc12 = zacc, acc13 = zacc;
        float zs0 = 0.f, zs1 = 0.f;
        // preload kf for ks=0
        short8 kf0c = *(const short8*)(Kh + (size_t)(l15)*8);
        short8 kf1c = *(const short8*)(Kh + (size_t)(16 + l15)*8);
#pragma unroll 1
        for (int ks = 0; ks < 7; ++ks) {
            f32x4 e00 = mfma_bf16(kf0c, qf0, zacc);
            f32x4 e01 = mfma_bf16(kf1c, qf0, zacc);
            f32x4 e10 = mfma_bf16(kf0c, qf1, zacc);
            f32x4 e11 = mfma_bf16(kf1c, qf1, zacc);
            // prefetch next iteration's kf (wrap on last; hidden under the exps)
            int ksn = (ks == 6) ? 0 : ks + 1;
            short8 kf0n = *(const short8*)(Kh + (size_t)(ksn*32 + l15)*8);
            short8 kf1n = *(const short8*)(Kh + (size_t)(ksn*32 + 16 + l15)*8);
            float a00[4], a01[4], a10[4], a11[4];
#pragma unroll
            for (int g = 0; g < 4; ++g) {
                a00[g] = __builtin_amdgcn_exp2f(e00[g]);
                a01[g] = __builtin_amdgcn_exp2f(e01[g]);
                a10[g] = __builtin_amdgcn_exp2f(e10[g]);
                a11[g] = __builtin_amdgcn_exp2f(e11[g]);
            }
            if (HM && (ch0 >> 1) == ks) {    // diag tile for ch0
                if ((ch0 & 1) == 0) {
#pragma unroll
                    for (int g = 0; g < 4; ++g) if (lg*4 + g == l15) a00[g] = 0.f;
                } else {
#pragma unroll
                    for (int g = 0; g < 4; ++g) if (lg*4 + g == l15) a01[g] = 0.f;
                }
            }
            if (HM && do1 && (ch1 >> 1) == ks) {  // diag tile for ch1
                if ((ch1 & 1) == 0) {
#pragma unroll
                    for (int g = 0; g < 4; ++g) if (lg*4 + g == l15) a10[g] = 0.f;
                } else {
#pragma unroll
                    for (int g = 0; g < 4; ++g) if (lg*4 + g == l15) a11[g] = 0.f;
                }
            }
            zs0 += ((a00[0]+a00[1]) + (a00[2]+a00[3])) + ((a01[0]+a01[1]) + (a01[2]+a01[3]));
            zs1 += ((a10[0]+a10[1]) + (a10[2]+a10[3])) + ((a11[0]+a11[1]) + (a11[2]+a11[3]));
            // af regs k=0..7 <-> u' = ks*32 + lg*8 + k -> this lane's own quads, direct pack.
            int4 i0, i1;
            i0.x = (int)packbf(a00[0], a00[1]); i0.y = (int)packbf(a00[2], a00[3]);
            i0.z = (int)packbf(a01[0], a01[1]); i0.w = (int)packbf(a01[2], a01[3]);
            i1.x = (int)packbf(a10[0], a10[1]); i1.y = (int)packbf(a10[2], a10[3]);
            i1.z = (int)packbf(a11[0], a11[1]); i1.w = (int)packbf(a11[2], a11[3]);
            short8 af0 = *(short8*)&i0;
            short8 af1 = *(short8*)&i1;
            {
                short8 vf0 = *(const short8*)((const char*)Vt + (size_t)(l15)*512       + vswz(l15,      ks*4 + lg));
                short8 vf1 = *(const short8*)((const char*)Vt + (size_t)(16 + l15)*512  + vswz(16 + l15, ks*4 + lg));
                short8 vf2 = *(const short8*)((const char*)Vt + (size_t)(32 + l15)*512  + vswz(32 + l15, ks*4 + lg));
                short8 vf3 = *(const short8*)((const char*)Vt + (size_t)(48 + l15)*512  + vswz(48 + l15, ks*4 + lg));
                acc00 = mfma_bf16(vf0, af0, acc00);
                acc10 = mfma_bf16(vf0, af1, acc10);
                acc01 = mfma_bf16(vf1, af0, acc01);
                acc11 = mfma_bf16(vf1, af1, acc11);
                acc02 = mfma_bf16(vf2, af0, acc02);
                acc12 = mfma_bf16(vf2, af1, acc12);
                acc03 = mfma_bf16(vf3, af0, acc03);
                acc13 = mfma_bf16(vf3, af1, acc13);
            }
            kf0c = kf0n; kf1c = kf1n;
        }
        // z row-sums
        zs0 += __shfl_xor(zs0, 16);
        zs0 += __shfl_xor(zs0, 32);
        zs1 += __shfl_xor(zs1, 16);
        zs1 += __shfl_xor(zs1, 32);
        if (lg == 0) {
            Zt[ch0*16 + l15] = zs0;
            if (do1) Zt[ch1*16 + l15] = zs1;
        }
        // stores: lane (l15=row, lg) writes 4 consecutive channels per ct
        {
            int pos = ch0*16 + l15;
            f32x4 av[4] = {acc00, acc01, acc02, acc03};
#pragma unroll
            for (int ct = 0; ct < 4; ++ct) {
                ushort4 pk;
                pk.x = f2bf(av[ct][0]); pk.y = f2bf(av[ct][1]);
                pk.z = f2bf(av[ct][2]); pk.w = f2bf(av[ct][3]);
                *(ushort4*)(op + (size_t)pos*64 + ct*16 + lg*4) = pk;
            }
        }
        if (do1) {
            int pos = ch1*16 + l15;
            f32x4 av[4] = {acc10, acc11, acc12, acc13};
#pragma unroll
            for (int ct = 0; ct < 4; ++ct) {
                ushort4 pk;
                pk.x = f2bf(av[ct][0]); pk.y = f2bf(av[ct][1]);
                pk.z = f2bf(av[ct][2]); pk.w = f2bf(av[ct][3]);
                *(ushort4*)(op + (size_t)pos*64 + ct*16 + lg*4) = pk;
            }
        }
    }
    __builtin_amdgcn_s_setprio(0);
}

// ---------------- final: out[b][c][v][t] = x*(1+y2) + (outA + outB) * g/(ZH+ZW) ----------------
__global__ __launch_bounds__(256) void k_final(const float* __restrict__ x,
                                               const ushort* __restrict__ outA,
                                               const ushort* __restrict__ outB,
                                               const float* __restrict__ ZHt,
                                               const float* __restrict__ ZWt,
                                               const float* __restrict__ gammap,
                                               const float* __restrict__ y2,
                                               float* __restrict__ out)
{
    __shared__ float Ls[2][16][65];
    __shared__ float sc[64];
    const int b = blockIdx.z;
    const int v0 = blockIdx.y*16, t0 = blockIdx.x*16;
    const int tid = threadIdx.x;
    const float g = gammap[0];
    if (tid < 64) sc[tid] = 1.f + y2[b*64 + tid];

    const int tl = tid >> 4, cg = tid & 15;   // stage: 16 t-rows x 16 c-quads
    const int tg = tid & 3, cw = tid >> 2;    // write: 64 c-rows x 4 float4

    const ushort* pA = outA + (size_t)b*NN*64;
    const ushort* pB = outB + (size_t)b*NN*64;
    __syncthreads();

    for (int vl = 0; vl < 16; ++vl) {
        const int v = v0 + vl;
        const int buf = vl & 1;
        {   // stage: comb[tl][c] = (A + B)*zi
            const ushort* a4 = pA + ((size_t)(t0 + tl)*224 + v)*64 + cg*4;
            const ushort* b4 = pB + ((size_t)v*224 + (t0 + tl))*64 + cg*4;
            uint2 ra = *(const uint2*)a4;
            uint2 rb = *(const uint2*)b4;
            const ushort* qa = (const ushort*)&ra;
            const ushort* qb = (const ushort*)&rb;
            float zh = ZHt[((size_t)(b*224 + t0 + tl))*224 + v];
            float zw = ZWt[((size_t)(b*224 + v))*224 + t0 + tl];
            float zi = g * __builtin_amdgcn_rcpf(zh + zw);
#pragma unroll
            for (int j = 0; j < 4; ++j)
                Ls[buf][tl][cg*4 + j] = (bf2f(qa[j]) + bf2f(qb[j])) * zi;
        }
        __syncthreads();
        {   // write: out rows [c][v][t0..t0+15], fused with x*(1+y2)
            float s = sc[cw];
            size_t idx = (size_t)(b*64 + cw)*NN + (size_t)v*224 + t0 + tg*4;
            float4 xv = *(const float4*)(x + idx);
            float4 o;
            o.x = xv.x*s + Ls[buf][tg*4+0][cw];
            o.y = xv.y*s + Ls[buf][tg*4+1][cw];
            o.z = xv.z*s + Ls[buf][tg*4+2][cw];
            o.w = xv.w*s + Ls[buf][tg*4+3][cw];
            *(float4*)(out + idx) = o;
        }
    }
}

// ---------------- launcher ----------------
extern "C" void kernel_launch(void* const* d_in, const int* in_sizes, int n_in,
                              void* d_out, int out_size, void* d_ws, size_t ws_size,
                              hipStream_t stream)
{
    const float* x  = (const float*)d_in[0];
    const float* Wq = (const float*)d_in[1];
    const float* bq = (const float*)d_in[2];
    const float* Wk = (const float*)d_in[3];
    const float* bk = (const float*)d_in[4];
    const float* Wv = (const float*)d_in[5];
    const float* bv = (const float*)d_in[6];
    const float* gm = (const float*)d_in[7];
    const float* W1 = (const float*)d_in[8];
    const float* W2 = (const float*)d_in[9];
    float* out = (float*)d_out;

    constexpr size_t QSZ = (size_t)BB*NN*CQv;
    constexpr size_t VSZ = (size_t)BB*NN*CC;
    constexpr size_t SSZ = (size_t)BB*NN;

    ushort* qB = (ushort*)d_ws;
    ushort* kB = qB + QSZ;
    ushort* vB = kB + QSZ;
    ushort* qA = vB + VSZ;
    ushort* kA = qA + QSZ;
    ushort* outA = kA + QSZ;
    ushort* outB = outA + VSZ;
    float*  ZHt = (float*)(outB + VSZ);
    float*  ZWt = ZHt + SSZ;
    float*  partial = ZWt + SSZ;       // BB*196*64 = 50176 floats
    float*  y2 = partial + (size_t)BB*196*64;
    (void)ws_size; (void)in_sizes; (void)n_in; (void)out_size;

    k_qkv<<<BB*196, 256, 0, stream>>>(x, Wq, bq, Wk, bk, Wv, bv, qB, kB, vB, partial);
    k_tq<<<dim3(7,7,9), 256, 0, stream>>>((const uint4*)qB, (const uint4*)kB, (uint4*)qA, (uint4*)kA,
                                          partial, W1, W2, y2);

    k_pv<<<2*BB*224, 256, 0, stream>>>(qA, kA, qB, kB, vB, outA, outB, ZHt, ZWt);

    k_final<<<dim3(14,14,BB), 256, 0, stream>>>(x, outA, outB, ZHt, ZWt, gm, y2, out);
}

// Round 16
// 107.968 us; speedup vs baseline: 1.0360x; 1.0205x over previous
//
#include <hip/hip_runtime.h>
#include <math.h>

#define CC 64
#define CQv 8
#define CRv 4
#define BB 4
#define RR 224
#define TT 224
#define NN (RR*TT)   // 50176
#define LOG2E 1.4426950408889634f

typedef __attribute__((ext_vector_type(8))) short short8;
typedef __attribute__((ext_vector_type(4))) float f32x4;

__device__ __forceinline__ f32x4 mfma_bf16(short8 a, short8 b, f32x4 c){
    return __builtin_amdgcn_mfma_f32_16x16x32_bf16(a, b, c, 0, 0, 0);
}

__device__ __forceinline__ ushort f2bf(float f){
    union { float f; unsigned u; } v; v.f = f;
    unsigned r = v.u + 0x7fffu + ((v.u >> 16) & 1u);
    return (ushort)(r >> 16);
}
__device__ __forceinline__ float bf2f(ushort u){
    return __uint_as_float((unsigned)u << 16);
}
// pack two f32 as truncated bf16 pair: [lo=a, hi=b]
__device__ __forceinline__ unsigned packbf(float a, float b){
    return __builtin_amdgcn_perm(__float_as_uint(b), __float_as_uint(a), 0x07060302u);
}
// balanced XOR swizzle: 512B rows (32 slots of 16B)
__device__ __forceinline__ int vswz(int row, int uslot){
    return (uslot ^ (row & 7) ^ ((row >> 3) & 7)) << 4;
}

// ---------------- K1: q,k,v 1x1 convs via MFMA + per-block mean partials ----------------
// qB[b][pos][8], kB[b][pos][8] (k pre-scaled by log2e), vB[b][pos][64]  (bf16)
__global__ __launch_bounds__(256) void k_qkv(
    const float* __restrict__ x,
    const float* __restrict__ Wq, const float* __restrict__ bq,
    const float* __restrict__ Wk, const float* __restrict__ bk,
    const float* __restrict__ Wv, const float* __restrict__ bv,
    ushort* __restrict__ qB, ushort* __restrict__ kB, ushort* __restrict__ vB,
    float* __restrict__ partial)
{
    const int tid = threadIdx.x;
    const int w = tid >> 6, l = tid & 63, l15 = l & 15, lg = l >> 4;
    const int blk = blockIdx.x;
    const int b = blk / 196, pb = blk - b*196;
    const int n0 = pb*256;
    const float* xb = x + (size_t)b*CC*NN;

    short8 afr[5][2];
#pragma unroll
    for (int ot = 0; ot < 5; ++ot) {
        int oo = ot*16 + l15;
        const float* wr = (oo < 8) ? (Wq + oo*64)
                        : (oo < 16) ? (Wk + (oo-8)*64)
                                    : (Wv + (oo-16)*64);
        float scl = (oo >= 8 && oo < 16) ? LOG2E : 1.0f;
#pragma unroll
        for (int ks = 0; ks < 2; ++ks) {
            const float* p = wr + ks*32 + lg*8;
            float4 w0 = *(const float4*)p, w1 = *(const float4*)(p+4);
            short8 f;
            f[0]=f2bf(w0.x*scl); f[1]=f2bf(w0.y*scl); f[2]=f2bf(w0.z*scl); f[3]=f2bf(w0.w*scl);
            f[4]=f2bf(w1.x*scl); f[5]=f2bf(w1.y*scl); f[6]=f2bf(w1.z*scl); f[7]=f2bf(w1.w*scl);
            afr[ot][ks] = f;
        }
    }
    f32x4 binit[5];
#pragma unroll
    for (int ot = 0; ot < 5; ++ot) {
        const float* bp;
        float scl = 1.0f;
        if (ot == 0) { bp = (lg < 2) ? (bq + lg*4) : (bk + (lg-2)*4); if (lg >= 2) scl = LOG2E; }
        else           bp = bv + (ot-1)*16 + lg*4;
        float4 bb4 = *(const float4*)bp;
        binit[ot] = (f32x4){bb4.x*scl, bb4.y*scl, bb4.z*scl, bb4.w*scl};
    }

    float msum[16];
#pragma unroll
    for (int i = 0; i < 16; ++i) msum[i] = 0.f;

#pragma unroll
    for (int j = 0; j < 4; ++j) {
        int n = n0 + (w*4 + j)*16 + l15;
        short8 bfr[2];
#pragma unroll
        for (int ks = 0; ks < 2; ++ks) {
            const float* xp = xb + (size_t)(ks*32 + lg*8)*NN + n;
            short8 f;
#pragma unroll
            for (int e = 0; e < 8; ++e) {
                float xv = xp[(size_t)e*NN];
                f[e] = f2bf(xv);
                msum[ks*8 + e] += xv;
            }
            bfr[ks] = f;
        }
#pragma unroll
        for (int ot = 0; ot < 5; ++ot) {
            f32x4 acc = binit[ot];
            acc = mfma_bf16(afr[ot][0], bfr[0], acc);
            acc = mfma_bf16(afr[ot][1], bfr[1], acc);
            ushort4 pk;
            pk.x = f2bf(acc[0]); pk.y = f2bf(acc[1]);
            pk.z = f2bf(acc[2]); pk.w = f2bf(acc[3]);
            if (ot == 0) {
                ushort* dst = (lg < 2) ? (qB + ((size_t)b*NN + n)*8 + lg*4)
                                       : (kB + ((size_t)b*NN + n)*8 + (lg-2)*4);
                *(ushort4*)dst = pk;
            } else {
                int oc = (ot-1)*16 + lg*4;
                *(ushort4*)(vB + ((size_t)b*NN + n)*64 + oc) = pk;
            }
        }
    }

#pragma unroll
    for (int i = 0; i < 16; ++i) {
        float s = msum[i];
        s += __shfl_xor(s, 1); s += __shfl_xor(s, 2);
        s += __shfl_xor(s, 4); s += __shfl_xor(s, 8);
        msum[i] = s;
    }
    __shared__ float msums[4][4][16];
    if (l15 == 0) {
#pragma unroll
        for (int i = 0; i < 16; ++i) msums[w][lg][i] = msum[i];
    }
    __syncthreads();
    if (tid < 64) {
        int c = tid;
        int lgi = (c >> 3) & 3, ii = (c >> 5)*8 + (c & 7);
        float t = msums[0][lgi][ii] + msums[1][lgi][ii] + msums[2][lgi][ii] + msums[3][lgi][ii];
        partial[(size_t)blk*64 + c] = t;
    }
}

// ---------------- transpose q/k (z<8) + SE branch (z==8, one block) ----------------
__global__ __launch_bounds__(256) void k_tq(const uint4* __restrict__ qs, const uint4* __restrict__ ks,
                                            uint4* __restrict__ qd, uint4* __restrict__ kd,
                                            const float* __restrict__ partial,
                                            const float* __restrict__ W1, const float* __restrict__ W2,
                                            float* __restrict__ y2)
{
    int z = blockIdx.z;
    if (z == 8) {
        if (blockIdx.x || blockIdx.y) return;
        __shared__ float mean_s[4][64];
        int tid = threadIdx.x;
        int b = tid >> 6, c = tid & 63;
        float s = 0.f;
        for (int i = 0; i < 196; ++i) s += partial[((size_t)(b*196 + i))*64 + c];
        mean_s[b][c] = s * (1.0f/NN);
        __syncthreads();
        float h[CRv];
#pragma unroll
        for (int j = 0; j < CRv; ++j) {
            float t = 0.f;
#pragma unroll
            for (int cc = 0; cc < CC; ++cc) t += W1[j*CC + cc] * mean_s[b][cc];
            h[j] = fmaxf(t, 0.f);
        }
        float s2 = 0.f;
#pragma unroll
        for (int j = 0; j < CRv; ++j) s2 += W2[c*CRv + j] * h[j];
        y2[tid] = 1.f/(1.f + __expf(-s2));
        return;
    }
    __shared__ uint4 tile[32][33];
    int b = z & 3;
    const uint4* sp = ((z >= 4) ? ks : qs) + (size_t)b*NN;
    uint4*       dp = ((z >= 4) ? kd : qd) + (size_t)b*NN;
    int t0 = blockIdx.x*32, r0 = blockIdx.y*32;
    int tx = threadIdx.x & 31, ty = threadIdx.x >> 5;
#pragma unroll
    for (int j = 0; j < 4; ++j) { int lr = ty + 8*j; tile[lr][tx] = sp[(size_t)(r0+lr)*224 + t0 + tx]; }
    __syncthreads();
#pragma unroll
    for (int j = 0; j < 4; ++j) { int lt = ty + 8*j; dp[(size_t)(t0+lt)*224 + r0 + tx] = tile[tx][lt]; }
}

// ---------------- PV via MFMA: chunk pairs, permuted-V, kf rotation prefetch ----------------
// BEST MEASURED CONFIG (round 13, 108.4us). Lever ledger from A/B rounds:
//   bpermute-delete +9us, chunk-pairing +5us, kf-prefetch +1.5us,
//   4-chunk-merge -3.5us (VGPR 52->84, occupancy 27->20%), setprio -1.8us (lockstep waves).
// ks loop stays unroll 1 (rounds 8-10: full unroll / tight caps -> scratch spill).
// SPILL SENTINEL: FETCH_SIZE must stay ~31MB.
__global__ __launch_bounds__(256, 3) void k_pv(const ushort* __restrict__ qA, const ushort* __restrict__ kA,
                                               const ushort* __restrict__ qB, const ushort* __restrict__ kB,
                                               const ushort* __restrict__ vB,
                                               ushort* __restrict__ outA, ushort* __restrict__ outB,
                                               float* __restrict__ ZHt, float* __restrict__ ZWt)
{
    __shared__ __align__(16) ushort Vt[64*256];  // bf16 [c][u'], XOR-swizzled 512B rows (32 KB)
    __shared__ __align__(16) ushort Kh[224*8];   // bf16 K rows (3.5 KB)

    const int tid = threadIdx.x;
    const int bid = blockIdx.x;
    const bool HM = bid < BB*224;
    const int blk = HM ? bid : bid - BB*224;
    const int b = blk / 224, o = blk - b*224;
    const ushort* Qsrc = (HM ? qA : qB) + (size_t)blk*1792;
    const ushort* Ksrc = (HM ? kA : kB) + (size_t)blk*1792;
    ushort* op = (HM ? outA : outB) + (size_t)blk*14336;
    float*  Zt = (HM ? ZHt : ZWt) + (size_t)blk*224;

    // ---- stage V^T with permuted u: u = ks*32 + th*16 + quad*4 + g  ->  u' = ks*32 + quad*8 + th*4 + g
    {
        const uint4* vbase = (const uint4*)vB;
        for (int gi = tid; gi < 448; gi += 256) {
            int ublk = gi >> 3, sub = gi & 7;
            int u0 = ublk << 2;
            size_t base, stride;
            if (HM) { base = ((size_t)b*NN + (size_t)u0*224 + o)*8 + sub; stride = 1792; }
            else    { base = ((size_t)blk*224 + u0)*8 + sub;              stride = 8;    }
            uint4 r0 = vbase[base], r1 = vbase[base+stride], r2 = vbase[base+2*stride], r3 = vbase[base+3*stride];
            const ushort* p0 = (const ushort*)&r0;
            const ushort* p1 = (const ushort*)&r1;
            const ushort* p2 = (const ushort*)&r2;
            const ushort* p3 = (const ushort*)&r3;
            int ks   = ublk >> 3;
            int th   = (ublk >> 2) & 1;
            int quad = ublk & 3;
            int half = th * 8;
#pragma unroll
            for (int j = 0; j < 8; ++j) {
                int c = sub*8 + j;
                ushort4 col; col.x = p0[j]; col.y = p1[j]; col.z = p2[j]; col.w = p3[j];
                *(ushort4*)((char*)Vt + c*512 + vswz(c, ks*4 + quad) + half) = col;
            }
        }
    }
    if (tid < 224) ((uint4*)Kh)[tid] = ((const uint4*)Ksrc)[tid];
    __syncthreads();

    const int w = tid >> 6, l = tid & 63;
    const int l15 = l & 15, lg = l >> 4;
    const short8 zfr = {0,0,0,0,0,0,0,0};
    const f32x4 zacc = {0.f,0.f,0.f,0.f};

#pragma unroll 1
    for (int p = 0; p < 2; ++p) {
        const int ch0 = w + p*8;
        const int ch1 = ch0 + 4;
        const bool do1 = (ch1 < 14);
        short8 qf0 = zfr, qf1 = zfr;
        if (lg == 0) {
            qf0 = *(const short8*)(Qsrc + (size_t)(ch0*16 + l15)*8);
            if (do1) qf1 = *(const short8*)(Qsrc + (size_t)(ch1*16 + l15)*8);
        }
        f32x4 acc00 = zacc, acc01 = zacc, acc02 = zacc, acc03 = zacc;
        f32x4 acc10 = zacc, acc11 = zacc, acc12 = zacc, acc13 = zacc;
        float zs0 = 0.f, zs1 = 0.f;
        // preload kf for ks=0
        short8 kf0c = *(const short8*)(Kh + (size_t)(l15)*8);
        short8 kf1c = *(const short8*)(Kh + (size_t)(16 + l15)*8);
#pragma unroll 1
        for (int ks = 0; ks < 7; ++ks) {
            f32x4 e00 = mfma_bf16(kf0c, qf0, zacc);
            f32x4 e01 = mfma_bf16(kf1c, qf0, zacc);
            f32x4 e10 = mfma_bf16(kf0c, qf1, zacc);
            f32x4 e11 = mfma_bf16(kf1c, qf1, zacc);
            // prefetch next iteration's kf (wrap on last; hidden under the exps)
            int ksn = (ks == 6) ? 0 : ks + 1;
            short8 kf0n = *(const short8*)(Kh + (size_t)(ksn*32 + l15)*8);
            short8 kf1n = *(const short8*)(Kh + (size_t)(ksn*32 + 16 + l15)*8);
            float a00[4], a01[4], a10[4], a11[4];
#pragma unroll
            for (int g = 0; g < 4; ++g) {
                a00[g] = __builtin_amdgcn_exp2f(e00[g]);
                a01[g] = __builtin_amdgcn_exp2f(e01[g]);
                a10[g] = __builtin_amdgcn_exp2f(e10[g]);
                a11[g] = __builtin_amdgcn_exp2f(e11[g]);
            }
            if (HM && (ch0 >> 1) == ks) {    // diag tile for ch0
                if ((ch0 & 1) == 0) {
#pragma unroll
                    for (int g = 0; g < 4; ++g) if (lg*4 + g == l15) a00[g] = 0.f;
                } else {
#pragma unroll
                    for (int g = 0; g < 4; ++g) if (lg*4 + g == l15) a01[g] = 0.f;
                }
            }
            if (HM && do1 && (ch1 >> 1) == ks) {  // diag tile for ch1
                if ((ch1 & 1) == 0) {
#pragma unroll
                    for (int g = 0; g < 4; ++g) if (lg*4 + g == l15) a10[g] = 0.f;
                } else {
#pragma unroll
                    for (int g = 0; g < 4; ++g) if (lg*4 + g == l15) a11[g] = 0.f;
                }
            }
            zs0 += ((a00[0]+a00[1]) + (a00[2]+a00[3])) + ((a01[0]+a01[1]) + (a01[2]+a01[3]));
            zs1 += ((a10[0]+a10[1]) + (a10[2]+a10[3])) + ((a11[0]+a11[1]) + (a11[2]+a11[3]));
            // af regs k=0..7 <-> u' = ks*32 + lg*8 + k -> this lane's own quads, direct pack.
            int4 i0, i1;
            i0.x = (int)packbf(a00[0], a00[1]); i0.y = (int)packbf(a00[2], a00[3]);
            i0.z = (int)packbf(a01[0], a01[1]); i0.w = (int)packbf(a01[2], a01[3]);
            i1.x = (int)packbf(a10[0], a10[1]); i1.y = (int)packbf(a10[2], a10[3]);
            i1.z = (int)packbf(a11[0], a11[1]); i1.w = (int)packbf(a11[2], a11[3]);
            short8 af0 = *(short8*)&i0;
            short8 af1 = *(short8*)&i1;
            {
                short8 vf0 = *(const short8*)((const char*)Vt + (size_t)(l15)*512       + vswz(l15,      ks*4 + lg));
                short8 vf1 = *(const short8*)((const char*)Vt + (size_t)(16 + l15)*512  + vswz(16 + l15, ks*4 + lg));
                short8 vf2 = *(const short8*)((const char*)Vt + (size_t)(32 + l15)*512  + vswz(32 + l15, ks*4 + lg));
                short8 vf3 = *(const short8*)((const char*)Vt + (size_t)(48 + l15)*512  + vswz(48 + l15, ks*4 + lg));
                acc00 = mfma_bf16(vf0, af0, acc00);
                acc10 = mfma_bf16(vf0, af1, acc10);
                acc01 = mfma_bf16(vf1, af0, acc01);
                acc11 = mfma_bf16(vf1, af1, acc11);
                acc02 = mfma_bf16(vf2, af0, acc02);
                acc12 = mfma_bf16(vf2, af1, acc12);
                acc03 = mfma_bf16(vf3, af0, acc03);
                acc13 = mfma_bf16(vf3, af1, acc13);
            }
            kf0c = kf0n; kf1c = kf1n;
        }
        // z row-sums
        zs0 += __shfl_xor(zs0, 16);
        zs0 += __shfl_xor(zs0, 32);
        zs1 += __shfl_xor(zs1, 16);
        zs1 += __shfl_xor(zs1, 32);
        if (lg == 0) {
            Zt[ch0*16 + l15] = zs0;
            if (do1) Zt[ch1*16 + l15] = zs1;
        }
        // stores: lane (l15=row, lg) writes 4 consecutive channels per ct
        {
            int pos = ch0*16 + l15;
            f32x4 av[4] = {acc00, acc01, acc02, acc03};
#pragma unroll
            for (int ct = 0; ct < 4; ++ct) {
                ushort4 pk;
                pk.x = f2bf(av[ct][0]); pk.y = f2bf(av[ct][1]);
                pk.z = f2bf(av[ct][2]); pk.w = f2bf(av[ct][3]);
                *(ushort4*)(op + (size_t)pos*64 + ct*16 + lg*4) = pk;
            }
        }
        if (do1) {
            int pos = ch1*16 + l15;
            f32x4 av[4] = {acc10, acc11, acc12, acc13};
#pragma unroll
            for (int ct = 0; ct < 4; ++ct) {
                ushort4 pk;
                pk.x = f2bf(av[ct][0]); pk.y = f2bf(av[ct][1]);
                pk.z = f2bf(av[ct][2]); pk.w = f2bf(av[ct][3]);
                *(ushort4*)(op + (size_t)pos*64 + ct*16 + lg*4) = pk;
            }
        }
    }
}

// ---------------- final: out[b][c][v][t] = x*(1+y2) + (outA + outB) * g/(ZH+ZW) ----------------
__global__ __launch_bounds__(256) void k_final(const float* __restrict__ x,
                                               const ushort* __restrict__ outA,
                                               const ushort* __restrict__ outB,
                                               const float* __restrict__ ZHt,
                                               const float* __restrict__ ZWt,
                                               const float* __restrict__ gammap,
                                               const float* __restrict__ y2,
                                               float* __restrict__ out)
{
    __shared__ float Ls[2][16][65];
    __shared__ float sc[64];
    const int b = blockIdx.z;
    const int v0 = blockIdx.y*16, t0 = blockIdx.x*16;
    const int tid = threadIdx.x;
    const float g = gammap[0];
    if (tid < 64) sc[tid] = 1.f + y2[b*64 + tid];

    const int tl = tid >> 4, cg = tid & 15;   // stage: 16 t-rows x 16 c-quads
    const int tg = tid & 3, cw = tid >> 2;    // write: 64 c-rows x 4 float4

    const ushort* pA = outA + (size_t)b*NN*64;
    const ushort* pB = outB + (size_t)b*NN*64;
    __syncthreads();

    for (int vl = 0; vl < 16; ++vl) {
        const int v = v0 + vl;
        const int buf = vl & 1;
        {   // stage: comb[tl][c] = (A + B)*zi
            const ushort* a4 = pA + ((size_t)(t0 + tl)*224 + v)*64 + cg*4;
            const ushort* b4 = pB + ((size_t)v*224 + (t0 + tl))*64 + cg*4;
            uint2 ra = *(const uint2*)a4;
            uint2 rb = *(const uint2*)b4;
            const ushort* qa = (const ushort*)&ra;
            const ushort* qb = (const ushort*)&rb;
            float zh = ZHt[((size_t)(b*224 + t0 + tl))*224 + v];
            float zw = ZWt[((size_t)(b*224 + v))*224 + t0 + tl];
            float zi = g * __builtin_amdgcn_rcpf(zh + zw);
#pragma unroll
            for (int j = 0; j < 4; ++j)
                Ls[buf][tl][cg*4 + j] = (bf2f(qa[j]) + bf2f(qb[j])) * zi;
        }
        __syncthreads();
        {   // write: out rows [c][v][t0..t0+15], fused with x*(1+y2)
            float s = sc[cw];
            size_t idx = (size_t)(b*64 + cw)*NN + (size_t)v*224 + t0 + tg*4;
            float4 xv = *(const float4*)(x + idx);
            float4 o;
            o.x = xv.x*s + Ls[buf][tg*4+0][cw];
            o.y = xv.y*s + Ls[buf][tg*4+1][cw];
            o.z = xv.z*s + Ls[buf][tg*4+2][cw];
            o.w = xv.w*s + Ls[buf][tg*4+3][cw];
            *(float4*)(out + idx) = o;
        }
    }
}

// ---------------- launcher ----------------
extern "C" void kernel_launch(void* const* d_in, const int* in_sizes, int n_in,
                              void* d_out, int out_size, void* d_ws, size_t ws_size,
                              hipStream_t stream)
{
    const float* x  = (const float*)d_in[0];
    const float* Wq = (const float*)d_in[1];
    const float* bq = (const float*)d_in[2];
    const float* Wk = (const float*)d_in[3];
    const float* bk = (const float*)d_in[4];
    const float* Wv = (const float*)d_in[5];
    const float* bv = (const float*)d_in[6];
    const float* gm = (const float*)d_in[7];
    const float* W1 = (const float*)d_in[8];
    const float* W2 = (const float*)d_in[9];
    float* out = (float*)d_out;

    constexpr size_t QSZ = (size_t)BB*NN*CQv;
    constexpr size_t VSZ = (size_t)BB*NN*CC;
    constexpr size_t SSZ = (size_t)BB*NN;

    ushort* qB = (ushort*)d_ws;
    ushort* kB = qB + QSZ;
    ushort* vB = kB + QSZ;
    ushort* qA = vB + VSZ;
    ushort* kA = qA + QSZ;
    ushort* outA = kA + QSZ;
    ushort* outB = outA + VSZ;
    float*  ZHt = (float*)(outB + VSZ);
    float*  ZWt = ZHt + SSZ;
    float*  partial = ZWt + SSZ;       // BB*196*64 = 50176 floats
    float*  y2 = partial + (size_t)BB*196*64;
    (void)ws_size; (void)in_sizes; (void)n_in; (void)out_size;

    k_qkv<<<BB*196, 256, 0, stream>>>(x, Wq, bq, Wk, bk, Wv, bv, qB, kB, vB, partial);
    k_tq<<<dim3(7,7,9), 256, 0, stream>>>((const uint4*)qB, (const uint4*)kB, (uint4*)qA, (uint4*)kA,
                                          partial, W1, W2, y2);

    k_pv<<<2*BB*224, 256, 0, stream>>>(qA, kA, qB, kB, vB, outA, outB, ZHt, ZWt);

    k_final<<<dim3(14,14,BB), 256, 0, stream>>>(x, outA, outB, ZHt, ZWt, gm, y2, out);
}